// Round 11
// baseline (163.986 us; speedup 1.0000x reference)
//
#include <hip/hip_runtime.h>
#include <hip/hip_bf16.h>

#define Dx 300
#define Mx 1024

// float-offsets into ws
#define OFF_REP    0
#define OFF_DEP    307200
#define OFF_HEAD   614400
#define OFF_ATTN   921600
#define OFF_BIAS   2723840      // fp32: bfc@+0, b1@+320, bf@+640
// ushort offsets from U = (ushort*)(ws + 1228800); all arrays k-stride 320,
// zero-padded (rows to 320 for W, k 300..319 everywhere)
#define U_BASE  1228800
#define XH      0               // [1024][320]
#define XL      327680
#define RFH     655360          // rep hi/lo [1024][320]
#define RFL     983040
#define ATH     1310720         // attn hi/lo [1024][320]
#define ATL     1638400
#define WFCH    1966080         // [320][320] each
#define WFCL    2068480
#define W1H     2170880
#define W1L     2273280
#define W2H     2375680
#define W2L     2478080
#define WF1H    2580480
#define WF1L    2682880
#define WF2H    2785280
#define WF2L    2887680

typedef __attribute__((ext_vector_type(8))) short short8;
typedef __attribute__((ext_vector_type(4))) float f32x4;

__device__ __forceinline__ float bf2f(unsigned short u) {
    union { unsigned int i; float f; } v; v.i = ((unsigned int)u) << 16; return v.f;
}
__device__ __forceinline__ unsigned short f2bf(float x) {   // RNE
    union { float f; unsigned int i; } u; u.f = x;
    unsigned int r = u.i + 0x7FFFu + ((u.i >> 16) & 1u);
    return (unsigned short)(r >> 16);
}
__device__ __forceinline__ int detect_bf16(const void* w) {
    const unsigned short* u = (const unsigned short*)w;
    int ok = 1;
    #pragma unroll
    for (int t = 0; t < 64; ++t) { float v = bf2f(u[t]); ok &= (fabsf(v) < 1.0f) ? 1 : 0; }
    return ok;
}
__device__ __forceinline__ float ldf(const void* p, int idx, int isbf) {
    return isbf ? bf2f(((const unsigned short*)p)[idx]) : ((const float*)p)[idx];
}

// ---------------------------------------------------------------------------
// k_prep: RNE hi/lo split of X and the 5 weight matrices into padded [.][320]
// arrays + fp32 biases. Linear map, fully coalesced. grid 3284 x 256.
// ---------------------------------------------------------------------------
__global__ __launch_bounds__(256) void k_prep(
        const void* __restrict__ Xv,  const void* __restrict__ Wfc,
        const void* __restrict__ W1,  const void* __restrict__ W2,
        const void* __restrict__ Wf1, const void* __restrict__ Wf2,
        const void* __restrict__ bfc, const void* __restrict__ b1,
        const void* __restrict__ bfv, float* __restrict__ ws) {
    __shared__ int s_isbf;
    if (threadIdx.x == 0) s_isbf = detect_bf16(Wfc);
    __syncthreads();
    const int isbf = s_isbf;
    const unsigned int idx = blockIdx.x * 256 + threadIdx.x;
    unsigned short* U = (unsigned short*)(ws + U_BASE);
    if (idx < 327680u) {                       // X: [1024][320]
        int m = idx / 320, k = idx - m * 320;
        float v = (k < 300) ? ldf(Xv, m * 300 + k, isbf) : 0.f;
        unsigned short h = f2bf(v);
        U[XH + idx] = h;
        U[XL + idx] = f2bf(v - bf2f(h));
    } else if (idx < 839680u) {                // 5 x W: [320][320]
        unsigned int j = idx - 327680u;
        int widx = j / 102400; j -= widx * 102400;
        int n = j / 320, k = j - n * 320;
        const void* src = (widx == 0) ? Wfc : (widx == 1) ? W1 : (widx == 2) ? W2
                        : (widx == 3) ? Wf1 : Wf2;
        float v = (n < 300 && k < 300) ? ldf(src, n * 300 + k, isbf) : 0.f;
        unsigned short h = f2bf(v);
        int base = WFCH + widx * 204800;       // H then L per matrix (102400 apart)
        U[base + n * 320 + k] = h;
        U[base + 102400 + n * 320 + k] = f2bf(v - bf2f(h));
    } else if (idx < 840640u) {                // biases
        int j = idx - 839680u;
        int wb = j / 320, o = j - wb * 320;
        const void* src = (wb == 0) ? bfc : (wb == 1 ? b1 : bfv);
        ws[OFF_BIAS + j] = (o < 300) ? ldf(src, o, isbf) : 0.f;
    }
}

// ---------------------------------------------------------------------------
// Barrier-free register MFMA GEMM. Wave w of 4 owns one 16x16 output tile.
// Lane l: A row = m0+(l&15), B row = nrow, k-offset (l>>4)*8. All operands
// pre-split & zero-padded: 4 aligned 16-B loads + 3 MFMA per 32-k step.
// ---------------------------------------------------------------------------
#define K_STEP(AHp, ALp, BHp, BLp, o)                                          \
    {                                                                          \
        short8 a_h = *(const short8*)((AHp) + (o));                            \
        short8 a_l = *(const short8*)((ALp) + (o));                            \
        short8 b_h = *(const short8*)((BHp) + (o));                            \
        short8 b_l = *(const short8*)((BLp) + (o));                            \
        acc = __builtin_amdgcn_mfma_f32_16x16x32_bf16(a_h, b_h, acc, 0, 0, 0); \
        acc = __builtin_amdgcn_mfma_f32_16x16x32_bf16(a_h, b_l, acc, 0, 0, 0); \
        acc = __builtin_amdgcn_mfma_f32_16x16x32_bf16(a_l, b_h, acc, 0, 0, 0); \
    }

// k_mm1: rep = elu(X @ Wfc^T + bfc). grid 320 = 64mt x 5nt.
__global__ __launch_bounds__(256) void k_mm1(float* __restrict__ ws) {
    const int tid = threadIdx.x, w = tid >> 6, l = tid & 63;
    const int mt = blockIdx.x / 5, nt = blockIdx.x % 5;
    const int m0 = mt * 16;
    const int mrow = m0 + (l & 15);
    const int nrow = nt * 64 + w * 16 + (l & 15);   // < 320
    const int koff = (l >> 4) * 8;
    unsigned short* U = (unsigned short*)(ws + U_BASE);
    const unsigned short* ah = U + XH + mrow * 320 + koff;
    const unsigned short* al = U + XL + mrow * 320 + koff;
    const unsigned short* bh = U + WFCH + nrow * 320 + koff;
    const unsigned short* bl = U + WFCL + nrow * 320 + koff;
    f32x4 acc = {0.f, 0.f, 0.f, 0.f};
    #pragma unroll 5
    for (int ks = 0; ks < 10; ++ks) K_STEP(ah, al, bh, bl, ks * 32)
    if (nrow < 300) {
        float bb = ws[OFF_BIAS + nrow];
        #pragma unroll
        for (int r = 0; r < 4; ++r) {
            int m_g = m0 + (l >> 4) * 4 + r;
            float v = acc[r] + bb;
            v = v > 0.f ? v : (__expf(v) - 1.f);
            ws[OFF_REP + m_g * 300 + nrow] = v;
            unsigned short h = f2bf(v);
            U[RFH + m_g * 320 + nrow] = h;
            U[RFL + m_g * 320 + nrow] = f2bf(v - bf2f(h));
        }
    } else {                                    // zero the k-pad of rep h/l
        #pragma unroll
        for (int r = 0; r < 4; ++r) {
            int m_g = m0 + (l >> 4) * 4 + r;
            U[RFH + m_g * 320 + nrow] = 0;
            U[RFL + m_g * 320 + nrow] = 0;
        }
    }
}

// k_mm2: dep = rep@W1^T + b1 ; head = rep@W2^T. grid 640 = 64mt x 10nt.
__global__ __launch_bounds__(256) void k_mm2(float* __restrict__ ws) {
    const int tid = threadIdx.x, w = tid >> 6, l = tid & 63;
    const int mt = blockIdx.x / 10, nt = blockIdx.x % 10;
    const int m0 = mt * 16;
    const int mrow = m0 + (l & 15);
    const int nrow = nt * 64 + w * 16 + (l & 15);   // 0..639
    const int koff = (l >> 4) * 8;
    unsigned short* U = (unsigned short*)(ws + U_BASE);
    const unsigned short* ah = U + RFH + mrow * 320 + koff;
    const unsigned short* al = U + RFL + mrow * 320 + koff;
    const int wsel = (nrow < 320);
    const int wrow = wsel ? nrow : nrow - 320;
    const unsigned short* bh = U + (wsel ? W1H : W2H) + wrow * 320 + koff;
    const unsigned short* bl = U + (wsel ? W1L : W2L) + wrow * 320 + koff;
    f32x4 acc = {0.f, 0.f, 0.f, 0.f};
    #pragma unroll 5
    for (int ks = 0; ks < 10; ++ks) K_STEP(ah, al, bh, bl, ks * 32)
    if (nrow < 300) {
        float bb = ws[OFF_BIAS + 320 + nrow];
        #pragma unroll
        for (int r = 0; r < 4; ++r) {
            int m_g = m0 + (l >> 4) * 4 + r;
            ws[OFF_DEP + m_g * 300 + nrow] = acc[r] + bb;
        }
    } else if (nrow >= 320 && nrow < 620) {
        #pragma unroll
        for (int r = 0; r < 4; ++r) {
            int m_g = m0 + (l >> 4) * 4 + r;
            ws[OFF_HEAD + m_g * 300 + (nrow - 320)] = acc[r];
        }
    }
}

// ---------------------------------------------------------------------------
// k_attn: single-pass branchless, fixed shift m=C (round-4 proven).
// grid 512, 320 thr. Epilogue also emits attn hi/lo; pad lanes zero-fill.
// ---------------------------------------------------------------------------
__global__ __launch_bounds__(320) void k_attn(
        float* __restrict__ ws, const int* __restrict__ mask) {
    const float* dep  = ws + OFF_DEP;
    const float* head = ws + OFF_HEAD;
    const float* rep  = ws + OFF_REP;
    unsigned short* U = (unsigned short*)(ws + U_BASE);
    __shared__ float mkf[256];
    const int blk = blockIdx.x;
    const int b = blk >> 7;
    const int tile = blk & 127;
    const int u = tile >> 1;
    const int i0 = (tile & 1) ? (254 - 2 * u) : (2 * u);
    const int tid = threadIdx.x;
    if (tid < 256) mkf[tid] = (float)mask[b * 256 + tid];
    __syncthreads();
    const int d = tid;
    const int base = b * 256;
    if (d >= 300) {                              // zero k-pad of attn h/l
        U[ATH + (base + i0) * 320 + d] = 0;
        U[ATL + (base + i0) * 320 + d] = 0;
        U[ATH + (base + i0 + 1) * 320 + d] = 0;
        U[ATL + (base + i0 + 1) * 320 + d] = 0;
        return;
    }

    const float hv0 = head[(base + i0) * Dx + d];
    const float hv1 = head[(base + i0 + 1) * Dx + d];
    const float pw0 = __expf(0.4f * hv0);
    const float pw1 = __expf(0.4f * hv1);

    float s0 = 0.f, r0 = 0.f, s1 = 0.f, r1 = 0.f;
    {
        const int j = i0 + 1;
        float dv = dep[(base + j) * Dx + d];
        float rv = rep[(base + j) * Dx + d];
        float mk = mkf[j];
        float ex = __expf(0.4f * dv);
        float u0 = fmaf(ex, pw0, 1.0f);
        float e0 = __expf(-10.0f * __builtin_amdgcn_rcpf(u0));
        float em0 = e0 * mk;
        s0 += em0; r0 = fmaf(em0, rv, r0);
    }
    const float* dp = dep + base * Dx + d;
    const float* rp = rep + base * Dx + d;
    #pragma unroll 4
    for (int j = i0 + 2; j < 256; ++j) {
        float dv = dp[j * Dx];
        float rv = rp[j * Dx];
        float mk = mkf[j];
        float ex = __expf(0.4f * dv);
        float u0 = fmaf(ex, pw0, 1.0f);
        float u1 = fmaf(ex, pw1, 1.0f);
        float e0 = __expf(-10.0f * __builtin_amdgcn_rcpf(u0));
        float e1 = __expf(-10.0f * __builtin_amdgcn_rcpf(u1));
        float em0 = e0 * mk;
        float em1 = e1 * mk;
        s0 += em0; r0 = fmaf(em0, rv, r0);
        s1 += em1; r1 = fmaf(em1, rv, r1);
    }
    const float den0 = s0 + (s0 == 0.f ? 1.f : 0.f) + 1e-20f;
    const float den1 = s1 + (s1 == 0.f ? 1.f : 0.f) + 1e-20f;
    const float a0 = r0 / den0, a1 = r1 / den1;
    ws[OFF_ATTN + (base + i0) * Dx + d]     = a0;
    ws[OFF_ATTN + (base + i0 + 1) * Dx + d] = a1;
    unsigned short h0 = f2bf(a0), h1 = f2bf(a1);
    U[ATH + (base + i0) * 320 + d] = h0;
    U[ATL + (base + i0) * 320 + d] = f2bf(a0 - bf2f(h0));
    U[ATH + (base + i0 + 1) * 320 + d] = h1;
    U[ATL + (base + i0 + 1) * 320 + d] = f2bf(a1 - bf2f(h1));
}

// ---------------------------------------------------------------------------
// k_mm3: gate = sigmoid(rep@Wf1^T + attn@Wf2^T + bf); blend; mask; store.
// grid 320 = 64mt x 5nt; 20 K-steps: first 10 rep x Wf1, next 10 attn x Wf2.
// ---------------------------------------------------------------------------
__global__ __launch_bounds__(256) void k_mm3(
        float* __restrict__ ws, const void* __restrict__ Wdet,
        const int* __restrict__ mask, void* __restrict__ outv) {
    __shared__ int s_isbf;
    if (threadIdx.x == 0) s_isbf = detect_bf16(Wdet);
    __syncthreads();
    const int isbf = s_isbf;
    const int tid = threadIdx.x, w = tid >> 6, l = tid & 63;
    const int mt = blockIdx.x / 5, nt = blockIdx.x % 5;
    const int m0 = mt * 16;
    const int mrow = m0 + (l & 15);
    const int nrow = nt * 64 + w * 16 + (l & 15);   // < 320
    const int koff = (l >> 4) * 8;
    unsigned short* U = (unsigned short*)(ws + U_BASE);
    const unsigned short* a1h = U + RFH + mrow * 320 + koff;
    const unsigned short* a1l = U + RFL + mrow * 320 + koff;
    const unsigned short* b1h = U + WF1H + nrow * 320 + koff;
    const unsigned short* b1l = U + WF1L + nrow * 320 + koff;
    const unsigned short* a2h = U + ATH + mrow * 320 + koff;
    const unsigned short* a2l = U + ATL + mrow * 320 + koff;
    const unsigned short* b2h = U + WF2H + nrow * 320 + koff;
    const unsigned short* b2l = U + WF2L + nrow * 320 + koff;
    f32x4 acc = {0.f, 0.f, 0.f, 0.f};
    #pragma unroll 5
    for (int ks = 0; ks < 10; ++ks) K_STEP(a1h, a1l, b1h, b1l, ks * 32)
    #pragma unroll 5
    for (int ks = 0; ks < 10; ++ks) K_STEP(a2h, a2l, b2h, b2l, ks * 32)
    if (nrow < 300) {
        float bb = ws[OFF_BIAS + 640 + nrow];
        #pragma unroll
        for (int r = 0; r < 4; ++r) {
            int m_g = m0 + (l >> 4) * 4 + r;
            float gp = acc[r] + bb;
            float gate = 1.0f / (1.0f + __expf(-gp));
            float rv = ws[OFF_REP  + m_g * 300 + nrow];
            float av = ws[OFF_ATTN + m_g * 300 + nrow];
            float res = (gate * rv + (1.0f - gate) * av) * (float)mask[m_g];
            if (isbf) ((__hip_bfloat16*)outv)[m_g * 300 + nrow] = __float2bfloat16(res);
            else      ((float*)outv)[m_g * 300 + nrow] = res;
        }
    }
}

extern "C" void kernel_launch(void* const* d_in, const int* in_sizes, int n_in,
                              void* d_out, int out_size, void* d_ws, size_t ws_size,
                              hipStream_t stream) {
    const void* X   = d_in[0];
    const int*  msk = (const int*)d_in[1];
    const void* Wfc = d_in[2];
    const void* bfc = d_in[3];
    const void* W1  = d_in[4];
    const void* W2  = d_in[5];
    const void* b1  = d_in[6];
    const void* Wf1 = d_in[7];
    const void* Wf2 = d_in[8];
    const void* bfv = d_in[9];
    float* ws = (float*)d_ws;

    hipLaunchKernelGGL(k_prep, dim3(3284), dim3(256), 0, stream,
                       X, Wfc, W1, W2, Wf1, Wf2, bfc, b1, bfv, ws);
    hipLaunchKernelGGL(k_mm1,  dim3(320), dim3(256), 0, stream, ws);
    hipLaunchKernelGGL(k_mm2,  dim3(640), dim3(256), 0, stream, ws);
    hipLaunchKernelGGL(k_attn, dim3(512), dim3(320), 0, stream, ws, msk);
    hipLaunchKernelGGL(k_mm3,  dim3(320), dim3(256), 0, stream,
                       ws, Wfc, msk, d_out);
}

// Round 12
// 152.491 us; speedup vs baseline: 1.0754x; 1.0754x over previous
//
#include <hip/hip_runtime.h>
#include <hip/hip_bf16.h>

#define Dx 300
#define Mx 1024

// float-offsets into ws
#define OFF_REP    0
#define OFF_DEP    307200      // holds exd = exp(0.4*dep)
#define OFF_HEAD   614400
#define OFF_ATTN   921600

typedef __attribute__((ext_vector_type(8))) short short8;
typedef __attribute__((ext_vector_type(4))) float f32x4;

union S8 { unsigned int u[4]; unsigned short s[8]; short8 v; };

__device__ __forceinline__ float bf2f(unsigned short u) {
    union { unsigned int i; float f; } v; v.i = ((unsigned int)u) << 16; return v.f;
}
__device__ __forceinline__ unsigned short f2bf(float x) {   // round-half-up
    union { float f; unsigned int i; } u; u.f = x;
    return (unsigned short)((u.i + 0x8000u) >> 16);
}
__device__ __forceinline__ int detect_bf16(const void* w) {
    const unsigned short* u = (const unsigned short*)w;
    int ok = 1;
    #pragma unroll
    for (int t = 0; t < 64; ++t) { float v = bf2f(u[t]); ok &= (fabsf(v) < 1.0f) ? 1 : 0; }
    return ok;
}
__device__ __forceinline__ float ldf(const void* p, int idx, int isbf) {
    return isbf ? bf2f(((const unsigned short*)p)[idx]) : ((const float*)p)[idx];
}

// 8 consecutive fp32 with bounds (pads 0)
__device__ __forceinline__ void load8f(const float* rowp, int kb, int kmax,
                                       int valid, float* x) {
    if (valid && kb + 8 <= kmax) {
        float4 a = *(const float4*)(rowp + kb);
        float4 b = *(const float4*)(rowp + kb + 4);
        x[0]=a.x; x[1]=a.y; x[2]=a.z; x[3]=a.w;
        x[4]=b.x; x[5]=b.y; x[6]=b.z; x[7]=b.w;
    } else {
        #pragma unroll
        for (int j = 0; j < 8; ++j) {
            int k = kb + j;
            x[j] = (valid && k < kmax) ? rowp[k] : 0.f;
        }
    }
}

// pack 8 fp32 -> bf16x8 (round-half-up), ~2 ops/elem
__device__ __forceinline__ short8 pack8(const float* x) {
    S8 H;
    #pragma unroll
    for (int p = 0; p < 4; ++p) {
        union { float f; unsigned int i; } a, b;
        a.f = x[2*p]; b.f = x[2*p+1];
        H.u[p] = ((a.i + 0x8000u) >> 16) | ((b.i + 0x8000u) & 0xFFFF0000u);
    }
    return H.v;
}

// 8 consecutive bf16 with bounds
__device__ __forceinline__ short8 load8bf(const unsigned short* rowp, int kb,
                                          int kmax, int valid) {
    S8 R;
    if (valid && kb + 8 <= kmax) {
        ushort4 a = *(const ushort4*)(rowp + kb);
        ushort4 b = *(const ushort4*)(rowp + kb + 4);
        R.s[0]=a.x; R.s[1]=a.y; R.s[2]=a.z; R.s[3]=a.w;
        R.s[4]=b.x; R.s[5]=b.y; R.s[6]=b.z; R.s[7]=b.w;
    } else {
        #pragma unroll
        for (int j = 0; j < 8; ++j) {
            int k = kb + j;
            R.s[j] = (valid && k < kmax) ? rowp[k] : (unsigned short)0;
        }
    }
    return R.v;
}

// ---------------------------------------------------------------------------
// k12: fused rep + dep/head. grid 640 = 64mt x 10nt, 256 thr (4 waves).
// Phase A: block recomputes its 16x300 rep tile (X @ Wfc^T + bfc, elu),
//          stages bf16 in LDS; nt==0 stores fp32 rep to ws.
// Phase B: dep/head 16x64 tile; dep epilogue stores exd = exp(0.4*dep).
// ---------------------------------------------------------------------------
__global__ __launch_bounds__(256) void k12(
        const void* __restrict__ Xv, const void* __restrict__ Wfc,
        const void* __restrict__ bfc, const void* __restrict__ W1,
        const void* __restrict__ W2,  const void* __restrict__ b1,
        float* __restrict__ ws) {
    __shared__ __align__(16) unsigned short repB[16][328];
    __shared__ int s_isbf;
    const int tid = threadIdx.x;
    if (tid == 0) s_isbf = detect_bf16(Wfc);
    for (int i = tid; i < 16 * 28; i += 256) {       // zero k-pad cols 300..327
        int m = i / 28, n = 300 + (i % 28);
        repB[m][n] = 0;
    }
    __syncthreads();
    const int isbf = s_isbf;
    const int w = tid >> 6, l = tid & 63;
    const int mt = blockIdx.x / 10, nt = blockIdx.x % 10;
    const int m0 = mt * 16;
    const int lm = l & 15, koff = (l >> 4) * 8;

    // A-fragments from X (held in registers for whole rep phase)
    short8 xa[10];
    if (isbf) {
        const unsigned short* Xp = (const unsigned short*)Xv + (m0 + lm) * 300;
        #pragma unroll
        for (int ks = 0; ks < 10; ++ks) xa[ks] = load8bf(Xp, ks*32 + koff, 300, 1);
    } else {
        const float* Xp = (const float*)Xv + (m0 + lm) * 300;
        #pragma unroll
        for (int ks = 0; ks < 10; ++ks) {
            float t[8]; load8f(Xp, ks*32 + koff, 300, 1, t);
            xa[ks] = pack8(t);
        }
    }

    // rep subtiles ns = w + 4q (19 subtiles over N=300->304)
    #pragma unroll
    for (int q = 0; q < 5; ++q) {
        const int ns = w + 4 * q;
        if (ns <= 18) {
            const int nb = ns * 16 + lm;
            const int ncl = nb < 300 ? nb : 299;
            f32x4 racc = {0.f, 0.f, 0.f, 0.f};
            if (isbf) {
                const unsigned short* Wp = (const unsigned short*)Wfc + ncl * 300;
                #pragma unroll
                for (int ks = 0; ks < 10; ++ks) {
                    short8 b = load8bf(Wp, ks*32 + koff, 300, 1);
                    racc = __builtin_amdgcn_mfma_f32_16x16x32_bf16(xa[ks], b, racc, 0, 0, 0);
                }
            } else {
                const float* Wp = (const float*)Wfc + ncl * 300;
                #pragma unroll
                for (int ks = 0; ks < 10; ++ks) {
                    float t[8]; load8f(Wp, ks*32 + koff, 300, 1, t);
                    short8 b = pack8(t);
                    racc = __builtin_amdgcn_mfma_f32_16x16x32_bf16(xa[ks], b, racc, 0, 0, 0);
                }
            }
            if (nb < 300) {
                float bb = ldf(bfc, nb, isbf);
                #pragma unroll
                for (int r = 0; r < 4; ++r) {
                    int ml = (l >> 4) * 4 + r;
                    float v = racc[r] + bb;
                    v = v > 0.f ? v : (__expf(v) - 1.f);
                    if (nt == 0) ws[OFF_REP + (m0 + ml) * 300 + nb] = v;
                    repB[ml][nb] = f2bf(v);
                }
            }
        }
    }
    __syncthreads();

    // dep/head phase
    short8 ra[10];
    #pragma unroll
    for (int ks = 0; ks < 10; ++ks)
        ra[ks] = *(const short8*)&repB[lm][ks*32 + koff];
    const int ng = nt * 64 + w * 16 + lm;           // 0..639
    const int wsel = ng < 320;
    const int wrow = wsel ? ng : ng - 320;
    const int bval = wrow < 300;
    const int wcl = bval ? wrow : 0;
    f32x4 dacc = {0.f, 0.f, 0.f, 0.f};
    if (isbf) {
        const unsigned short* Wp = (const unsigned short*)(wsel ? W1 : W2) + wcl * 300;
        #pragma unroll
        for (int ks = 0; ks < 10; ++ks) {
            short8 b = load8bf(Wp, ks*32 + koff, 300, bval);
            dacc = __builtin_amdgcn_mfma_f32_16x16x32_bf16(ra[ks], b, dacc, 0, 0, 0);
        }
    } else {
        const float* Wp = (const float*)(wsel ? W1 : W2) + wcl * 300;
        #pragma unroll
        for (int ks = 0; ks < 10; ++ks) {
            float t[8]; load8f(Wp, ks*32 + koff, 300, bval, t);
            short8 b = pack8(t);
            dacc = __builtin_amdgcn_mfma_f32_16x16x32_bf16(ra[ks], b, dacc, 0, 0, 0);
        }
    }
    if (ng < 300) {
        float bb = ldf(b1, ng, isbf);
        #pragma unroll
        for (int r = 0; r < 4; ++r) {
            int mg = m0 + (l >> 4) * 4 + r;
            ws[OFF_DEP + mg * 300 + ng] = __expf(0.4f * (dacc[r] + bb));  // exd
        }
    } else if (ng >= 320 && ng < 620) {
        #pragma unroll
        for (int r = 0; r < 4; ++r) {
            int mg = m0 + (l >> 4) * 4 + r;
            ws[OFF_HEAD + mg * 300 + (ng - 320)] = dacc[r];
        }
    }
}

// ---------------------------------------------------------------------------
// k_attn: single-pass branchless, fixed shift m=C; consumes exd (one fewer
// exp in the inner loop). grid 512, 320 thr; 2-i tiles long/short interleaved.
// ---------------------------------------------------------------------------
__global__ __launch_bounds__(320) void k_attn(
        float* __restrict__ ws, const int* __restrict__ mask) {
    const float* exd  = ws + OFF_DEP;
    const float* head = ws + OFF_HEAD;
    const float* rep  = ws + OFF_REP;
    __shared__ float mkf[256];
    const int blk = blockIdx.x;
    const int b = blk >> 7;
    const int tile = blk & 127;
    const int u = tile >> 1;
    const int i0 = (tile & 1) ? (254 - 2 * u) : (2 * u);
    const int tid = threadIdx.x;
    if (tid < 256) mkf[tid] = (float)mask[b * 256 + tid];
    __syncthreads();
    const int d = tid;
    if (d >= Dx) return;
    const int base = b * 256;

    const float hv0 = head[(base + i0) * Dx + d];
    const float hv1 = head[(base + i0 + 1) * Dx + d];
    const float pw0 = __expf(0.4f * hv0);
    const float pw1 = __expf(0.4f * hv1);

    float s0 = 0.f, r0 = 0.f, s1 = 0.f, r1 = 0.f;
    {
        const int j = i0 + 1;
        float ex = exd[(base + j) * Dx + d];
        float rv = rep[(base + j) * Dx + d];
        float mk = mkf[j];
        float u0 = fmaf(ex, pw0, 1.0f);
        float e0 = __expf(-10.0f * __builtin_amdgcn_rcpf(u0));
        float em0 = e0 * mk;
        s0 += em0; r0 = fmaf(em0, rv, r0);
    }
    const float* ep = exd + base * Dx + d;
    const float* rp = rep + base * Dx + d;
    #pragma unroll 4
    for (int j = i0 + 2; j < 256; ++j) {
        float ex = ep[j * Dx];
        float rv = rp[j * Dx];
        float mk = mkf[j];
        float u0 = fmaf(ex, pw0, 1.0f);
        float u1 = fmaf(ex, pw1, 1.0f);
        float e0 = __expf(-10.0f * __builtin_amdgcn_rcpf(u0));
        float e1 = __expf(-10.0f * __builtin_amdgcn_rcpf(u1));
        float em0 = e0 * mk;
        float em1 = e1 * mk;
        s0 += em0; r0 = fmaf(em0, rv, r0);
        s1 += em1; r1 = fmaf(em1, rv, r1);
    }
    const float den0 = s0 + (s0 == 0.f ? 1.f : 0.f) + 1e-20f;
    const float den1 = s1 + (s1 == 0.f ? 1.f : 0.f) + 1e-20f;
    ws[OFF_ATTN + (base + i0) * Dx + d]     = r0 / den0;
    ws[OFF_ATTN + (base + i0 + 1) * Dx + d] = r1 / den1;
}

// ---------------------------------------------------------------------------
// k_mm3: gate = sigmoid(rep@Wf1^T + attn@Wf2^T + bf); blend; mask; store.
// grid 320 = 64mt x 5nt; register MFMA, single-bf16 operands.
// ---------------------------------------------------------------------------
__global__ __launch_bounds__(256) void k_mm3(
        const void* __restrict__ Wf1, const void* __restrict__ Wf2,
        const void* __restrict__ bfv, const int* __restrict__ mask,
        float* __restrict__ ws, void* __restrict__ outv) {
    __shared__ int s_isbf;
    if (threadIdx.x == 0) s_isbf = detect_bf16(Wf1);
    __syncthreads();
    const int isbf = s_isbf;
    const int tid = threadIdx.x, w = tid >> 6, l = tid & 63;
    const int mt = blockIdx.x / 5, nt = blockIdx.x % 5;
    const int m0 = mt * 16;
    const int lm = l & 15, koff = (l >> 4) * 8;
    const int mrow = m0 + lm;
    const int nrow = nt * 64 + w * 16 + lm;
    const int bval = nrow < 300;
    const int ncl = bval ? nrow : 0;
    const float* repp = ws + OFF_REP  + mrow * 300;
    const float* attp = ws + OFF_ATTN + mrow * 300;
    f32x4 acc = {0.f, 0.f, 0.f, 0.f};
    #pragma unroll 2
    for (int ks = 0; ks < 10; ++ks) {       // rep x Wf1
        const int kb = ks * 32 + koff;
        float ta[8]; load8f(repp, kb, 300, 1, ta);
        short8 a = pack8(ta);
        short8 bfr;
        if (isbf) bfr = load8bf((const unsigned short*)Wf1 + ncl * 300, kb, 300, bval);
        else { float tb[8]; load8f((const float*)Wf1 + ncl * 300, kb, 300, bval, tb); bfr = pack8(tb); }
        acc = __builtin_amdgcn_mfma_f32_16x16x32_bf16(a, bfr, acc, 0, 0, 0);
    }
    #pragma unroll 2
    for (int ks = 0; ks < 10; ++ks) {       // attn x Wf2
        const int kb = ks * 32 + koff;
        float ta[8]; load8f(attp, kb, 300, 1, ta);
        short8 a = pack8(ta);
        short8 bfr;
        if (isbf) bfr = load8bf((const unsigned short*)Wf2 + ncl * 300, kb, 300, bval);
        else { float tb[8]; load8f((const float*)Wf2 + ncl * 300, kb, 300, bval, tb); bfr = pack8(tb); }
        acc = __builtin_amdgcn_mfma_f32_16x16x32_bf16(a, bfr, acc, 0, 0, 0);
    }
    if (bval) {
        float bb = ldf(bfv, nrow, isbf);
        #pragma unroll
        for (int r = 0; r < 4; ++r) {
            int mg = m0 + (l >> 4) * 4 + r;
            float gp = acc[r] + bb;
            float gate = 1.0f / (1.0f + __expf(-gp));
            float rv = ws[OFF_REP  + mg * 300 + nrow];
            float av = ws[OFF_ATTN + mg * 300 + nrow];
            float res = (gate * rv + (1.0f - gate) * av) * (float)mask[mg];
            if (isbf) ((__hip_bfloat16*)outv)[mg * 300 + nrow] = __float2bfloat16(res);
            else      ((float*)outv)[mg * 300 + nrow] = res;
        }
    }
}

extern "C" void kernel_launch(void* const* d_in, const int* in_sizes, int n_in,
                              void* d_out, int out_size, void* d_ws, size_t ws_size,
                              hipStream_t stream) {
    const void* X   = d_in[0];
    const int*  msk = (const int*)d_in[1];
    const void* Wfc = d_in[2];
    const void* bfc = d_in[3];
    const void* W1  = d_in[4];
    const void* W2  = d_in[5];
    const void* b1  = d_in[6];
    const void* Wf1 = d_in[7];
    const void* Wf2 = d_in[8];
    const void* bfv = d_in[9];
    float* ws = (float*)d_ws;

    hipLaunchKernelGGL(k12,    dim3(640), dim3(256), 0, stream,
                       X, Wfc, bfc, W1, W2, b1, ws);
    hipLaunchKernelGGL(k_attn, dim3(512), dim3(320), 0, stream, ws, msk);
    hipLaunchKernelGGL(k_mm3,  dim3(320), dim3(256), 0, stream,
                       Wf1, Wf2, bfv, msk, ws, d_out);
}

// Round 13
// 137.426 us; speedup vs baseline: 1.1933x; 1.1096x over previous
//
#include <hip/hip_runtime.h>
#include <hip/hip_bf16.h>

#define Dx 300
#define Mx 1024

// float-offsets into ws
#define OFF_REP    0
#define OFF_DEP    307200      // holds exd = exp(0.4*(dep+b1))
#define OFF_HEAD   614400
#define OFF_ATTN   921600
// ushort arrays at U = (ushort*)(ws + 1228800): zero-padded [1024][320]
#define U_BASE     1228800
#define REPB       0
#define ATB        327680

typedef __attribute__((ext_vector_type(8))) short short8;
typedef __attribute__((ext_vector_type(4))) float f32x4;

union S8 { unsigned int u[4]; unsigned short s[8]; short8 v; };

__device__ __forceinline__ float bf2f(unsigned short u) {
    union { unsigned int i; float f; } v; v.i = ((unsigned int)u) << 16; return v.f;
}
__device__ __forceinline__ unsigned short f2bf(float x) {   // round-half-up
    union { float f; unsigned int i; } u; u.f = x;
    return (unsigned short)((u.i + 0x8000u) >> 16);
}
__device__ __forceinline__ int detect_bf16(const void* w) {
    const unsigned short* u = (const unsigned short*)w;
    int ok = 1;
    #pragma unroll
    for (int t = 0; t < 64; ++t) { float v = bf2f(u[t]); ok &= (fabsf(v) < 1.0f) ? 1 : 0; }
    return ok;
}
__device__ __forceinline__ float ldf(const void* p, int idx, int isbf) {
    return isbf ? bf2f(((const unsigned short*)p)[idx]) : ((const float*)p)[idx];
}

__device__ __forceinline__ void load8f(const float* rowp, int kb, int kmax,
                                       int valid, float* x) {
    if (valid && kb + 8 <= kmax) {
        float4 a = *(const float4*)(rowp + kb);
        float4 b = *(const float4*)(rowp + kb + 4);
        x[0]=a.x; x[1]=a.y; x[2]=a.z; x[3]=a.w;
        x[4]=b.x; x[5]=b.y; x[6]=b.z; x[7]=b.w;
    } else {
        #pragma unroll
        for (int j = 0; j < 8; ++j) {
            int k = kb + j;
            x[j] = (valid && k < kmax) ? rowp[k] : 0.f;
        }
    }
}
__device__ __forceinline__ short8 pack8(const float* x) {
    S8 H;
    #pragma unroll
    for (int p = 0; p < 4; ++p) {
        union { float f; unsigned int i; } a, b;
        a.f = x[2*p]; b.f = x[2*p+1];
        H.u[p] = ((a.i + 0x8000u) >> 16) | ((b.i + 0x8000u) & 0xFFFF0000u);
    }
    return H.v;
}
__device__ __forceinline__ short8 load8bf(const unsigned short* rowp, int kb,
                                          int kmax, int valid) {
    S8 R;
    if (valid && kb + 8 <= kmax) {
        ushort4 a = *(const ushort4*)(rowp + kb);
        ushort4 b = *(const ushort4*)(rowp + kb + 4);
        R.s[0]=a.x; R.s[1]=a.y; R.s[2]=a.z; R.s[3]=a.w;
        R.s[4]=b.x; R.s[5]=b.y; R.s[6]=b.z; R.s[7]=b.w;
    } else {
        #pragma unroll
        for (int j = 0; j < 8; ++j) {
            int k = kb + j;
            R.s[j] = (valid && k < kmax) ? rowp[k] : (unsigned short)0;
        }
    }
    return R.v;
}
// load B fragment from weight row (either dtype), bf16-packed
__device__ __forceinline__ short8 loadB(const void* W, int row, int kb, int isbf,
                                        int valid) {
    if (isbf) return load8bf((const unsigned short*)W + row * 300, kb, 300, valid);
    float t[8];
    load8f((const float*)W + row * 300, kb, 300, valid, t);
    return pack8(t);
}

// ---------------------------------------------------------------------------
// k_mm1: rep = elu(X @ Wfc^T + bfc). grid 320 = 64mt x 5nt, 4 waves/block,
// wave w owns 16x16 tile. Emits rep fp32 + repB bf16 (zero-padded [1024][320]).
// ---------------------------------------------------------------------------
__global__ __launch_bounds__(256) void k_mm1(
        const void* __restrict__ Xv, const void* __restrict__ Wfc,
        const void* __restrict__ bfc, float* __restrict__ ws) {
    __shared__ int s_isbf;
    if (threadIdx.x == 0) s_isbf = detect_bf16(Wfc);
    __syncthreads();
    const int isbf = s_isbf;
    const int tid = threadIdx.x, w = tid >> 6, l = tid & 63;
    const int mt = blockIdx.x / 5, nt = blockIdx.x % 5;
    const int m0 = mt * 16, lm = l & 15, koff = (l >> 4) * 8;
    const int nrow = nt * 64 + w * 16 + lm;          // 0..319
    const int bval = nrow < 300;
    const int ncl = bval ? nrow : 0;
    unsigned short* U = (unsigned short*)(ws + U_BASE);
    f32x4 acc = {0.f, 0.f, 0.f, 0.f};
    if (isbf) {
        const unsigned short* Xp = (const unsigned short*)Xv + (m0 + lm) * 300;
        #pragma unroll
        for (int ks = 0; ks < 10; ++ks) {
            short8 a = load8bf(Xp, ks*32 + koff, 300, 1);
            short8 b = loadB(Wfc, ncl, ks*32 + koff, 1, bval);
            acc = __builtin_amdgcn_mfma_f32_16x16x32_bf16(a, b, acc, 0, 0, 0);
        }
    } else {
        const float* Xp = (const float*)Xv + (m0 + lm) * 300;
        #pragma unroll
        for (int ks = 0; ks < 10; ++ks) {
            float t[8]; load8f(Xp, ks*32 + koff, 300, 1, t);
            short8 a = pack8(t);
            short8 b = loadB(Wfc, ncl, ks*32 + koff, 0, bval);
            acc = __builtin_amdgcn_mfma_f32_16x16x32_bf16(a, b, acc, 0, 0, 0);
        }
    }
    if (bval) {
        float bb = ldf(bfc, nrow, isbf);
        #pragma unroll
        for (int r = 0; r < 4; ++r) {
            int mg = m0 + (l >> 4) * 4 + r;
            float v = acc[r] + bb;
            v = v > 0.f ? v : (__expf(v) - 1.f);
            ws[OFF_REP + mg * 300 + nrow] = v;
            U[REPB + mg * 320 + nrow] = f2bf(v);
        }
    } else {
        #pragma unroll
        for (int r = 0; r < 4; ++r) {
            int mg = m0 + (l >> 4) * 4 + r;
            U[REPB + mg * 320 + nrow] = 0;
        }
    }
}

// ---------------------------------------------------------------------------
// k_mm2: dep/head from repB (pre-packed A). grid 640 = 64mt x 10nt.
// dep epilogue stores exd = exp(0.4*(dep+b1)).
// ---------------------------------------------------------------------------
__global__ __launch_bounds__(256) void k_mm2(
        const void* __restrict__ W1, const void* __restrict__ W2,
        const void* __restrict__ b1, float* __restrict__ ws) {
    __shared__ int s_isbf;
    if (threadIdx.x == 0) s_isbf = detect_bf16(W1);
    __syncthreads();
    const int isbf = s_isbf;
    const int tid = threadIdx.x, w = tid >> 6, l = tid & 63;
    const int mt = blockIdx.x / 10, nt = blockIdx.x % 10;
    const int m0 = mt * 16, lm = l & 15, koff = (l >> 4) * 8;
    const int ng = nt * 64 + w * 16 + lm;            // 0..639
    const int wsel = ng < 320;
    const int wrow = wsel ? ng : ng - 320;
    const int bval = wrow < 300;
    const int wcl = bval ? wrow : 0;
    const void* Wp = wsel ? W1 : W2;
    const unsigned short* U = (const unsigned short*)(ws + U_BASE);
    const unsigned short* ap = U + REPB + (m0 + lm) * 320 + koff;
    f32x4 acc = {0.f, 0.f, 0.f, 0.f};
    #pragma unroll
    for (int ks = 0; ks < 10; ++ks) {
        short8 a = *(const short8*)(ap + ks * 32);
        short8 b = loadB(Wp, wcl, ks*32 + koff, isbf, bval);
        acc = __builtin_amdgcn_mfma_f32_16x16x32_bf16(a, b, acc, 0, 0, 0);
    }
    if (ng < 300) {
        float bb = ldf(b1, ng, isbf);
        #pragma unroll
        for (int r = 0; r < 4; ++r) {
            int mg = m0 + (l >> 4) * 4 + r;
            ws[OFF_DEP + mg * 300 + ng] = __expf(0.4f * (acc[r] + bb));
        }
    } else if (ng >= 320 && ng < 620) {
        #pragma unroll
        for (int r = 0; r < 4; ++r) {
            int mg = m0 + (l >> 4) * 4 + r;
            ws[OFF_HEAD + mg * 300 + (ng - 320)] = acc[r];
        }
    }
}

// ---------------------------------------------------------------------------
// k_attn: single-pass branchless, fixed shift m=C, consumes exd.
// Epilogue also emits padded bf16 atB; pad lanes (d>=300) zero-fill.
// grid 512, 320 thr; 2-i tiles long/short interleaved.
// ---------------------------------------------------------------------------
__global__ __launch_bounds__(320) void k_attn(
        float* __restrict__ ws, const int* __restrict__ mask) {
    const float* exd  = ws + OFF_DEP;
    const float* head = ws + OFF_HEAD;
    const float* rep  = ws + OFF_REP;
    unsigned short* U = (unsigned short*)(ws + U_BASE);
    __shared__ float mkf[256];
    const int blk = blockIdx.x;
    const int b = blk >> 7;
    const int tile = blk & 127;
    const int u = tile >> 1;
    const int i0 = (tile & 1) ? (254 - 2 * u) : (2 * u);
    const int tid = threadIdx.x;
    if (tid < 256) mkf[tid] = (float)mask[b * 256 + tid];
    __syncthreads();
    const int d = tid;
    const int base = b * 256;
    if (d >= 300) {                                  // zero k-pad of atB
        U[ATB + (base + i0) * 320 + d] = 0;
        U[ATB + (base + i0 + 1) * 320 + d] = 0;
        return;
    }

    const float hv0 = head[(base + i0) * Dx + d];
    const float hv1 = head[(base + i0 + 1) * Dx + d];
    const float pw0 = __expf(0.4f * hv0);
    const float pw1 = __expf(0.4f * hv1);

    float s0 = 0.f, r0 = 0.f, s1 = 0.f, r1 = 0.f;
    {
        const int j = i0 + 1;
        float ex = exd[(base + j) * Dx + d];
        float rv = rep[(base + j) * Dx + d];
        float mk = mkf[j];
        float u0 = fmaf(ex, pw0, 1.0f);
        float e0 = __expf(-10.0f * __builtin_amdgcn_rcpf(u0));
        float em0 = e0 * mk;
        s0 += em0; r0 = fmaf(em0, rv, r0);
    }
    const float* ep = exd + base * Dx + d;
    const float* rp = rep + base * Dx + d;
    #pragma unroll 4
    for (int j = i0 + 2; j < 256; ++j) {
        float ex = ep[j * Dx];
        float rv = rp[j * Dx];
        float mk = mkf[j];
        float u0 = fmaf(ex, pw0, 1.0f);
        float u1 = fmaf(ex, pw1, 1.0f);
        float e0 = __expf(-10.0f * __builtin_amdgcn_rcpf(u0));
        float e1 = __expf(-10.0f * __builtin_amdgcn_rcpf(u1));
        float em0 = e0 * mk;
        float em1 = e1 * mk;
        s0 += em0; r0 = fmaf(em0, rv, r0);
        s1 += em1; r1 = fmaf(em1, rv, r1);
    }
    const float den0 = s0 + (s0 == 0.f ? 1.f : 0.f) + 1e-20f;
    const float den1 = s1 + (s1 == 0.f ? 1.f : 0.f) + 1e-20f;
    const float a0 = r0 / den0, a1 = r1 / den1;
    ws[OFF_ATTN + (base + i0) * Dx + d]     = a0;
    ws[OFF_ATTN + (base + i0 + 1) * Dx + d] = a1;
    U[ATB + (base + i0) * 320 + d]     = f2bf(a0);
    U[ATB + (base + i0 + 1) * 320 + d] = f2bf(a1);
}

// ---------------------------------------------------------------------------
// k_mm3: gate = sigmoid(rep@Wf1^T + attn@Wf2^T + bf); blend; mask; store.
// A operands pre-packed (repB/atB). grid 320 = 64mt x 5nt.
// ---------------------------------------------------------------------------
__global__ __launch_bounds__(256) void k_mm3(
        const void* __restrict__ Wf1, const void* __restrict__ Wf2,
        const void* __restrict__ bfv, const int* __restrict__ mask,
        float* __restrict__ ws, void* __restrict__ outv) {
    __shared__ int s_isbf;
    if (threadIdx.x == 0) s_isbf = detect_bf16(Wf1);
    __syncthreads();
    const int isbf = s_isbf;
    const int tid = threadIdx.x, w = tid >> 6, l = tid & 63;
    const int mt = blockIdx.x / 5, nt = blockIdx.x % 5;
    const int m0 = mt * 16, lm = l & 15, koff = (l >> 4) * 8;
    const int nrow = nt * 64 + w * 16 + lm;
    const int bval = nrow < 300;
    const int ncl = bval ? nrow : 0;
    const unsigned short* U = (const unsigned short*)(ws + U_BASE);
    const unsigned short* a1p = U + REPB + (m0 + lm) * 320 + koff;
    const unsigned short* a2p = U + ATB  + (m0 + lm) * 320 + koff;
    f32x4 acc = {0.f, 0.f, 0.f, 0.f};
    #pragma unroll
    for (int ks = 0; ks < 10; ++ks) {
        short8 a = *(const short8*)(a1p + ks * 32);
        short8 b = loadB(Wf1, ncl, ks*32 + koff, isbf, bval);
        acc = __builtin_amdgcn_mfma_f32_16x16x32_bf16(a, b, acc, 0, 0, 0);
    }
    #pragma unroll
    for (int ks = 0; ks < 10; ++ks) {
        short8 a = *(const short8*)(a2p + ks * 32);
        short8 b = loadB(Wf2, ncl, ks*32 + koff, isbf, bval);
        acc = __builtin_amdgcn_mfma_f32_16x16x32_bf16(a, b, acc, 0, 0, 0);
    }
    if (bval) {
        float bb = ldf(bfv, nrow, isbf);
        #pragma unroll
        for (int r = 0; r < 4; ++r) {
            int mg = m0 + (l >> 4) * 4 + r;
            float gp = acc[r] + bb;
            float gate = 1.0f / (1.0f + __expf(-gp));
            float rv = ws[OFF_REP  + mg * 300 + nrow];
            float av = ws[OFF_ATTN + mg * 300 + nrow];
            float res = (gate * rv + (1.0f - gate) * av) * (float)mask[mg];
            if (isbf) ((__hip_bfloat16*)outv)[mg * 300 + nrow] = __float2bfloat16(res);
            else      ((float*)outv)[mg * 300 + nrow] = res;
        }
    }
}

extern "C" void kernel_launch(void* const* d_in, const int* in_sizes, int n_in,
                              void* d_out, int out_size, void* d_ws, size_t ws_size,
                              hipStream_t stream) {
    const void* X   = d_in[0];
    const int*  msk = (const int*)d_in[1];
    const void* Wfc = d_in[2];
    const void* bfc = d_in[3];
    const void* W1  = d_in[4];
    const void* W2  = d_in[5];
    const void* b1  = d_in[6];
    const void* Wf1 = d_in[7];
    const void* Wf2 = d_in[8];
    const void* bfv = d_in[9];
    float* ws = (float*)d_ws;

    hipLaunchKernelGGL(k_mm1,  dim3(320), dim3(256), 0, stream, X, Wfc, bfc, ws);
    hipLaunchKernelGGL(k_mm2,  dim3(640), dim3(256), 0, stream, W1, W2, b1, ws);
    hipLaunchKernelGGL(k_attn, dim3(512), dim3(320), 0, stream, ws, msk);
    hipLaunchKernelGGL(k_mm3,  dim3(320), dim3(256), 0, stream,
                       Wf1, Wf2, bfv, msk, ws, d_out);
}